// Round 11
// baseline (29.240 us; speedup 1.0000x reference)
//
#include <hip/hip_runtime.h>
#include <hip/hip_bf16.h>
#include <math.h>

#define NB_TASKS 20
#define CLASSES_PER_TASK 100
#define N_COLS (NB_TASKS * CLASSES_PER_TASK)   // 2000
#define N_F4   (N_COLS / 4)                    // 500
#define F4_PER_TASK (CLASSES_PER_TASK / 4)     // 25
#define INV_TEMP (1.0f / 5.0f)
#define ROWS_PER_WAVE 4

typedef float vf4 __attribute__((ext_vector_type(4)));

__device__ __forceinline__ float rfl_f(float x) {
    return __int_as_float(__builtin_amdgcn_readfirstlane(__float_as_int(x)));
}

struct Top2 { int j1, j2; float w1, w2; };
struct Row10 { vf4 a0, a1, a2, a3, a4, b0, b1, b2, b3, b4; };

// issue all 10 gocls loads for one row (group g covers tasks 4k+g)
__device__ __forceinline__ Row10 load_row10(const float* grow, int grp, int s, int s2) {
    const vf4* p0 = (const vf4*)(grow + grp * CLASSES_PER_TASK);
    Row10 r;
    r.a0 = p0[s      ];  r.b0 = p0[s2      ];
    r.a1 = p0[s + 100];  r.b1 = p0[s2 + 100];
    r.a2 = p0[s + 200];  r.b2 = p0[s2 + 200];
    r.a3 = p0[s + 300];  r.b3 = p0[s2 + 300];
    r.a4 = p0[s + 400];  r.b4 = p0[s2 + 400];
    return r;
}

__device__ __forceinline__ float max8(vf4 x, vf4 y) {
    return fmaxf(fmaxf(fmaxf(x.x, x.y), fmaxf(x.z, x.w)),
                 fmaxf(fmaxf(y.x, y.y), fmaxf(y.z, y.w)));
}

// merge (m1,i1,m2,i2) with incoming (om1,oi1,om2,oi2); order: bigger value,
// tie -> smaller index (== jax top_k first-occurrence rule)
__device__ __forceinline__ void top2_merge(float& m1, int& i1, float& m2, int& i2,
                                           float om1, int oi1, float om2, int oi2) {
    const bool aF = (m1 > om1) || (m1 == om1 && i1 < oi1);
    const float t1 = aF ? m1 : om1;  const int t1i = aF ? i1 : oi1;
    const float l  = aF ? om1 : m1;  const int li  = aF ? oi1 : i1;
    const float c  = aF ? m2 : om2;  const int ci  = aF ? i2 : oi2;
    const bool lF = (l > c) || (l == c && li < ci);
    m1 = t1; i1 = t1i;
    m2 = lF ? l : c; i2 = lF ? li : ci;
}

// v: lane t<20 holds task t's value, lanes>=20 hold -INF. Depth-5 top-2
// butterfly with parallel sum-tree of exp(v/T) (no max-sub: |v/T|<=~1 here).
__device__ __forceinline__ Top2 softmax_top2(float v, float coef, int lane) {
    float ex = (lane < NB_TASKS) ? __expf(v * INV_TEMP) : 0.0f;
    float m1 = v, m2 = -INFINITY;
    int   i1 = lane, i2 = lane;
    float sum = ex;
    #pragma unroll
    for (int off = 16; off; off >>= 1) {
        const float om1 = __shfl_xor(m1, off);
        const int   oi1 = __shfl_xor(i1, off);
        const float om2 = __shfl_xor(m2, off);
        const int   oi2 = __shfl_xor(i2, off);
        sum += __shfl_xor(sum, off);             // independent tree, same depth
        top2_merge(m1, i1, m2, i2, om1, oi1, om2, oi2);
    }
    Top2 r;
    r.j1 = __builtin_amdgcn_readfirstlane(i1);
    r.j2 = __builtin_amdgcn_readfirstlane(i2);
    const float s  = rfl_f(sum);
    const float v1 = rfl_f(m1);
    const float v2 = rfl_f(m2);
    r.w1 = coef * __expf(v1 * INV_TEMP) / s;
    r.w2 = coef * __expf(v2 * INV_TEMP) / s;
    return r;
}

__device__ __forceinline__ void process_row(
    const Row10& c, float gv, float a,
    const vf4* __restrict__ din, vf4* __restrict__ dout,
    int lane, int half, int hs)
{
    // --- per-task max from the preloaded registers ---
    float cv = -INFINITY;
    const float mk0 = max8(c.a0, c.b0);
    const float mk1 = max8(c.a1, c.b1);
    const float mk2 = max8(c.a2, c.b2);
    const float mk3 = max8(c.a3, c.b3);
    const float mk4 = max8(c.a4, c.b4);
    const float mks[5] = {mk0, mk1, mk2, mk3, mk4};
    #pragma unroll
    for (int k = 0; k < 5; ++k) {
        float m = mks[k];
        #pragma unroll
        for (int off = 8; off; off >>= 1)
            m = fmaxf(m, __shfl_xor(m, off));    // butterfly within 16-lane group
        const float g2 = __shfl(m, (lane & 3) << 4);
        if ((lane >> 2) == k) cv = g2;           // lanes 0..19 collect task maxes
    }

    // --- both softmax paths (A could overlap reduce; chains are short now) ---
    const Top2 pa = softmax_top2(gv, a,        lane);
    const Top2 pb = softmax_top2(cv, 1.0f - a, lane);

    // fold duplicates
    const float wA1 = pa.w1 + ((pb.j1 == pa.j1) ? pb.w1 : 0.0f)
                            + ((pb.j2 == pa.j1) ? pb.w2 : 0.0f);
    const float wA2 = pa.w2 + ((pb.j1 == pa.j2) ? pb.w1 : 0.0f)
                            + ((pb.j2 == pa.j2) ? pb.w2 : 0.0f);
    const bool bo1 = (pb.j1 != pa.j1) && (pb.j1 != pa.j2);
    const bool bo2 = (pb.j2 != pa.j1) && (pb.j2 != pa.j2);

    const int   jA = half ? pa.j2 : pa.j1;
    const float wA = half ? wA2   : wA1;
    const int   jB = half ? pb.j2 : pb.j1;
    const float wB = half ? pb.w2 : pb.w1;
    const bool  bo = half ? bo2   : bo1;

    // packed top-k dol loads (2 instructions cover up to 4 regions)
    vf4 dA = {0, 0, 0, 0}, dB = {0, 0, 0, 0};
    if (hs < F4_PER_TASK) {
        dA = din[jA * F4_PER_TASK + hs];
        if (bo) dB = din[jB * F4_PER_TASK + hs];
    }

    // --- single-write output: zeros everywhere except top-k holes ---
    {
        const vf4 z = {0.0f, 0.0f, 0.0f, 0.0f};
        #pragma unroll
        for (int i = 0; i < (N_F4 + 63) / 64; ++i) {
            const int f = lane + 64 * i;
            if (f < N_F4) {
                const int task = f / F4_PER_TASK;
                const bool hole = (task == pa.j1) || (task == pa.j2) ||
                                  (task == pb.j1) || (task == pb.j2);
                if (!hole) __builtin_nontemporal_store(z, &dout[f]);
            }
        }
    }
    // weighted stores into the holes (each address written exactly once -> no fence)
    if (hs < F4_PER_TASK) {
        __builtin_nontemporal_store(dA * wA, &dout[jA * F4_PER_TASK + hs]);
        if (bo)
            __builtin_nontemporal_store(dB * wB, &dout[jB * F4_PER_TASK + hs]);
    }
}

__global__ __launch_bounds__(256) void mix_kernel(
    const float* __restrict__ gol,     // [B, 20]
    const float* __restrict__ gocls,   // [B, 2000]
    const float* __restrict__ dol,     // [B, 2000]
    const float* __restrict__ alpha_p, // [1]
    float* __restrict__ out,           // [B, 2000]
    int B)
{
    const int tid  = threadIdx.x;
    const int lane = tid & 63;
    const int wid  = blockIdx.x * 4 + (tid >> 6);
    const int row0 = wid * ROWS_PER_WAVE;
    if (row0 >= B) return;

    const int grp  = lane >> 4;                  // 16-lane group (reduce)
    const int s    = lane & 15;
    const int s2   = (s < 9) ? 16 + s : 0;       // dense 2nd load (redundant ok for max)
    const int half = lane >> 5;                  // 32-lane half (packed topk)
    const int hs   = lane & 31;

    const float a = alpha_p[0];

    #define GROW(r)  (gocls + (size_t)(r) * N_COLS)
    #define GV(r)    ((lane < NB_TASKS) ? gol[(size_t)(r) * NB_TASKS + lane] : -INFINITY)
    #define DIN(r)   ((const vf4*)(dol + (size_t)(r) * N_COLS))
    #define DOUT(r)  ((vf4*)(out + (size_t)(r) * N_COLS))

    // --- software pipeline: row r+1's 10 loads fly during row r's compute ---
    Row10 c0 = load_row10(GROW(row0 + 0), grp, s, s2);
    float g0 = GV(row0 + 0);

    Row10 c1 = load_row10(GROW(row0 + 1), grp, s, s2);
    float g1 = GV(row0 + 1);
    process_row(c0, g0, a, DIN(row0 + 0), DOUT(row0 + 0), lane, half, hs);

    Row10 c2 = load_row10(GROW(row0 + 2), grp, s, s2);
    float g2 = GV(row0 + 2);
    process_row(c1, g1, a, DIN(row0 + 1), DOUT(row0 + 1), lane, half, hs);

    Row10 c3 = load_row10(GROW(row0 + 3), grp, s, s2);
    float g3 = GV(row0 + 3);
    process_row(c2, g2, a, DIN(row0 + 2), DOUT(row0 + 2), lane, half, hs);

    process_row(c3, g3, a, DIN(row0 + 3), DOUT(row0 + 3), lane, half, hs);

    #undef GROW
    #undef GV
    #undef DIN
    #undef DOUT
}

extern "C" void kernel_launch(void* const* d_in, const int* in_sizes, int n_in,
                              void* d_out, int out_size, void* d_ws, size_t ws_size,
                              hipStream_t stream) {
    const float* gol   = (const float*)d_in[0];
    const float* gocls = (const float*)d_in[1];
    const float* dol   = (const float*)d_in[2];
    const float* alpha = (const float*)d_in[3];
    float* out = (float*)d_out;

    const int B = in_sizes[0] / NB_TASKS;  // 8192

    // 4 waves/block, 4 rows/wave -> 16 rows/block
    const int grid = (B + 16 - 1) / 16;    // 512 blocks
    hipLaunchKernelGGL(mix_kernel, dim3(grid), dim3(256), 0, stream,
                       gol, gocls, dol, alpha, out, B);
}

// Round 12
// 28.057 us; speedup vs baseline: 1.0422x; 1.0422x over previous
//
#include <hip/hip_runtime.h>
#include <hip/hip_bf16.h>
#include <math.h>

#define NB_TASKS 20
#define CLASSES_PER_TASK 100
#define N_COLS (NB_TASKS * CLASSES_PER_TASK)   // 2000
#define N_F4   (N_COLS / 4)                    // 500
#define F4_PER_TASK (CLASSES_PER_TASK / 4)     // 25
#define INV_TEMP (1.0f / 5.0f)
#define ROWS_PER_BLOCK 4

typedef float vf4 __attribute__((ext_vector_type(4)));

__device__ __forceinline__ float rfl_f(float x) {
    return __int_as_float(__builtin_amdgcn_readfirstlane(__float_as_int(x)));
}

struct Top2 { int j1, j2; float w1, w2; };

// v: lane t (t<20) holds value for task t; lanes 20..63 hold -INF.
// Returns wave-uniform top-2 indices and softmax weights (scaled by coef).
__device__ __forceinline__ Top2 softmax_top2(float v, float coef, int lane) {
    // argmax, min-index tiebreak (== jax top_k tie rule); data lives in lanes 0..31
    float v1 = v; int i1 = lane;
    #pragma unroll
    for (int off = 16; off; off >>= 1) {
        float ov = __shfl_xor(v1, off);
        int   oj = __shfl_xor(i1, off);
        if (ov > v1 || (ov == v1 && oj < i1)) { v1 = ov; i1 = oj; }
    }
    // second argmax, excluding lane i1
    float v2 = (lane == i1) ? -INFINITY : v;
    int   i2 = lane;
    #pragma unroll
    for (int off = 16; off; off >>= 1) {
        float ov = __shfl_xor(v2, off);
        int   oj = __shfl_xor(i2, off);
        if (ov > v2 || (ov == v2 && oj < i2)) { v2 = ov; i2 = oj; }
    }
    // softmax denominator: exp((v - max)/T); -INF lanes contribute 0
    float ex  = __expf((v - v1) * INV_TEMP);
    float sum = ex;
    #pragma unroll
    for (int off = 16; off; off >>= 1)
        sum += __shfl_xor(sum, off);

    Top2 r;
    r.j1 = __builtin_amdgcn_readfirstlane(i1);
    r.j2 = __builtin_amdgcn_readfirstlane(i2);
    float w1 = coef / sum;                        // exp(0) = 1
    float w2 = __expf((v2 - v1) * INV_TEMP) * w1;
    r.w1 = rfl_f(w1);
    r.w2 = rfl_f(w2);
    return r;
}

__global__ __launch_bounds__(256) void mix_kernel(
    const float* __restrict__ gol,     // [B, 20]
    const float* __restrict__ gocls,   // [B, 2000]
    const float* __restrict__ dol,     // [B, 2000]
    const float* __restrict__ alpha_p, // [1]
    float* __restrict__ out,           // [B, 2000]
    int B)
{
    const int tid  = threadIdx.x;
    const int lane = tid & 63;
    const int b    = blockIdx.x * ROWS_PER_BLOCK + (tid >> 6);
    if (b >= B) return;

    const int grp  = lane >> 4;   // 16-lane group: 0..3 (reduce phase)
    const int s    = lane & 15;
    const int half = lane >> 5;   // 32-lane half: 0..1 (packed topk phase)
    const int hs   = lane & 31;

    const vf4*   din  = (const vf4*)(dol + (size_t)b * N_COLS);
    vf4*         dout = (vf4*)(out + (size_t)b * N_COLS);
    const float* grow = gocls + (size_t)b * N_COLS;

    // --- ISSUE ALL 10 REDUCE LOADS FIRST: one base address, immediate
    //     offsets; 10 x dwordx4 in flight (~40 VGPR) = max per-wave MLP. ---
    // group g handles tasks 4k+g; second load made fully dense: lanes s>=9
    // re-read p[0] (in-range, redundant, harmless for max).
    const vf4* p0 = (const vf4*)(grow + grp * CLASSES_PER_TASK);
    const int  s2 = (s < 9) ? 16 + s : 0;
    vf4 va0 = p0[s      ];
    vf4 va1 = p0[s + 100];
    vf4 va2 = p0[s + 200];
    vf4 va3 = p0[s + 300];
    vf4 va4 = p0[s + 400];
    vf4 vb0 = p0[s2      ];
    vf4 vb1 = p0[s2 + 100];
    vf4 vb2 = p0[s2 + 200];
    vf4 vb3 = p0[s2 + 300];
    vf4 vb4 = p0[s2 + 400];

    // --- path A (gol): tiny load + shuffle chains, overlaps reduce loads ---
    const float a  = alpha_p[0];
    const float gv = (lane < NB_TASKS) ? gol[(size_t)b * NB_TASKS + lane] : -INFINITY;
    const Top2 pa = softmax_top2(gv, a, lane);

    // packed A-pair dol load: half 0 -> region pa.j1, half 1 -> pa.j2
    const int jA = half ? pa.j2 : pa.j1;
    vf4 dA = {0,0,0,0};
    if (hs < F4_PER_TASK) dA = din[jA * F4_PER_TASK + hs];

    // --- dense branch-free zero-blast of the whole row (NT stores) ---
    {
        const vf4 z = {0.0f, 0.0f, 0.0f, 0.0f};
        #pragma unroll
        for (int i = 0; i < (N_F4 + 63) / 64; ++i) {
            const int f = lane + 64 * i;
            if (f < N_F4) __builtin_nontemporal_store(z, &dout[f]);
        }
    }

    // --- reduce the 10 preloaded vectors: per-task max, 4 tasks/iter ---
    float cv = -INFINITY;
    vf4 vas[5] = {va0, va1, va2, va3, va4};
    vf4 vbs[5] = {vb0, vb1, vb2, vb3, vb4};
    #pragma unroll
    for (int k = 0; k < 5; ++k) {
        vf4 x = vas[k], y = vbs[k];
        float m = fmaxf(fmaxf(fmaxf(x.x, x.y), fmaxf(x.z, x.w)),
                        fmaxf(fmaxf(y.x, y.y), fmaxf(y.z, y.w)));
        #pragma unroll
        for (int off = 8; off; off >>= 1)          // butterfly within 16-lane group
            m = fmaxf(m, __shfl_xor(m, off));
        float g2 = __shfl(m, (lane & 3) << 4);     // lane 4k+g <- group g's max
        if ((lane >> 2) == k) cv = g2;             // lanes 0..19 collect task maxes
    }

    // --- path B (per-task gocls max) ---
    const Top2 pb = softmax_top2(cv, 1.0f - a, lane);

    // fold B weights into A where indices coincide
    const float wA1 = pa.w1 + ((pb.j1 == pa.j1) ? pb.w1 : 0.0f)
                            + ((pb.j2 == pa.j1) ? pb.w2 : 0.0f);
    const float wA2 = pa.w2 + ((pb.j1 == pa.j2) ? pb.w1 : 0.0f)
                            + ((pb.j2 == pa.j2) ? pb.w2 : 0.0f);
    const bool bo1 = (pb.j1 != pa.j1) && (pb.j1 != pa.j2);
    const bool bo2 = (pb.j2 != pa.j1) && (pb.j2 != pa.j2);

    const float wA = half ? wA2 : wA1;
    const int   jB = half ? pb.j2 : pb.j1;
    const float wB = half ? pb.w2 : pb.w1;
    const bool  bo = half ? bo2 : bo1;

    // packed B-pair dol load (one instruction, <=50 lanes)
    vf4 dB = {0,0,0,0};
    if (bo && hs < F4_PER_TASK) dB = din[jB * F4_PER_TASK + hs];

    // blast zeros must land before overwriting top-k regions
    asm volatile("s_waitcnt vmcnt(0)" ::: "memory");

    // packed tail stores: 2 instructions cover up to 4 regions
    if (hs < F4_PER_TASK) {
        __builtin_nontemporal_store(dA * wA, &dout[jA * F4_PER_TASK + hs]);
        if (bo)
            __builtin_nontemporal_store(dB * wB, &dout[jB * F4_PER_TASK + hs]);
    }
}

extern "C" void kernel_launch(void* const* d_in, const int* in_sizes, int n_in,
                              void* d_out, int out_size, void* d_ws, size_t ws_size,
                              hipStream_t stream) {
    const float* gol   = (const float*)d_in[0];
    const float* gocls = (const float*)d_in[1];
    const float* dol   = (const float*)d_in[2];
    const float* alpha = (const float*)d_in[3];
    float* out = (float*)d_out;

    const int B = in_sizes[0] / NB_TASKS;  // 8192

    const int grid = (B + ROWS_PER_BLOCK - 1) / ROWS_PER_BLOCK;
    hipLaunchKernelGGL(mix_kernel, dim3(grid), dim3(256), 0, stream,
                       gol, gocls, dol, alpha, out, B);
}